// Round 22
// baseline (220.387 us; speedup 1.0000x reference)
//
#include <hip/hip_runtime.h>
#include <hip/hip_bf16.h>

// GATv2 x2: N=100000, E=800000, IN=128, HID=32, H=4, OUT=16
//  r22: CAP 64 -> 16. Each node's bucket = exactly ONE 64B cache line, so
//  its ~8 random edge writes coalesce into a single line allocation
//  (25.6MB -> 6.4MB line traffic, L2-resident). Overflow (P(deg>16)~0.4%,
//  ~630 edges) handled exactly via ovf list scan in edge kernels.
//  Fused build+proj1 (r21), edge1/proj2/edge2 unchanged.

#define NEG_SLOPE 0.2f
#define CAP 16

typedef _Float16 f16;
typedef _Float16 f16x2 __attribute__((ext_vector_type(2)));
typedef _Float16 f16x4 __attribute__((ext_vector_type(4)));
typedef _Float16 f16x8 __attribute__((ext_vector_type(8)));
typedef float f32x4 __attribute__((ext_vector_type(4)));

// k_pre: b<256 -> Bh fragment-major, b<288 -> Bh2, b==288 -> attnh + zero
// ovf_cnt, b>=289 -> zero cnt.
__global__ __launch_bounds__(128) void k_pre(const float* __restrict__ W1s, const float* __restrict__ W1d,
                                             const float* __restrict__ W2s, const float* __restrict__ W2d,
                                             const float* __restrict__ attn1, const float* __restrict__ attn2,
                                             f16* __restrict__ Bh, f16* __restrict__ Bh2,
                                             f16* __restrict__ attnh, int* __restrict__ cnt,
                                             int* __restrict__ ovf_cnt, int n) {
    int b = blockIdx.x, k = threadIdx.x;
    if (b < 256) {
        float v = (b < 128) ? W1s[k * 128 + b] : W1d[k * 128 + (b - 128)];
        int idx = (((b >> 4) * 16 + (k >> 3)) * 16 + (b & 15)) * 8 + (k & 7);
        Bh[idx] = (f16)v;
    } else if (b < 288) {
        int c = b - 256;
        float v = (c < 16) ? W2s[k * 16 + c] : W2d[k * 16 + (c - 16)];
        Bh2[c * 128 + k] = (f16)v;
    } else if (b == 288) {
        attnh[k] = (f16)attn1[k];
        if (k < 16) attnh[128 + k] = (f16)attn2[k];
        if (k == 0) ovf_cnt[0] = 0;
    } else {
        int i = ((b - 289) * 128 + k) * 4;
        if (i < n) {
            int m = n - i;
            if (m > 4) m = 4;
            for (int j = 0; j < m; ++j) cnt[i + j] = 0;
        }
    }
}

// proj1 body: 32-row tile, both halves sequential, fragment-major B loads,
// LDS-transpose epilogue (r17, verified).
__device__ __forceinline__ void proj1_body(char* lds, int bid,
    const float* __restrict__ x, const f16* __restrict__ Bh,
    const float* __restrict__ bs, const float* __restrict__ bd,
    f16* __restrict__ hs, f16* __restrict__ hd, int n)
{
    char* alds = lds;
    char* elds = lds + 8192;
    int t = threadIdx.x;
    int row0 = bid * 32;

    {
        const float4* x4 = reinterpret_cast<const float4*>(x + (size_t)row0 * 128);
        int rows_here = n - row0; if (rows_here > 32) rows_here = 32;
        int max4 = rows_here * 32;
        #pragma unroll
        for (int i = 0; i < 4; ++i) {
            int idx = t + i * 256;
            float4 v = (idx < max4) ? x4[idx] : make_float4(0.f, 0.f, 0.f, 0.f);
            int row = idx >> 5, k = (idx & 31) * 4;
            int off = row * 256 + ((((k >> 3) ^ (row & 7)) & 15) << 4) + (k & 7) * 2;
            f16x4 h; h[0] = (f16)v.x; h[1] = (f16)v.y; h[2] = (f16)v.z; h[3] = (f16)v.w;
            *reinterpret_cast<f16x4*>(alds + off) = h;
        }
    }
    __syncthreads();

    int w = t >> 6, lane = t & 63;
    int n0w = w * 32;
    int lr = lane & 15;
    int kgrp = lane >> 4;
    int nc0 = kgrp * 4;

    for (int half = 0; half < 2; ++half) {
        f32x4 acc[2][2] = {};
        #pragma unroll
        for (int ks = 0; ks < 4; ++ks) {
            f16x8 b[2], a[2];
            #pragma unroll
            for (int nf = 0; nf < 2; ++nf) {
                int cg = half * 8 + w * 2 + nf;
                const f16* Bf = Bh + (size_t)cg * 2048 + ((ks * 4 + kgrp) * 16 + lr) * 8;
                b[nf] = *reinterpret_cast<const f16x8*>(Bf);
            }
            int k = ks * 32 + kgrp * 8;
            #pragma unroll
            for (int mf = 0; mf < 2; ++mf) {
                int row = mf * 16 + lr;
                int off = row * 256 + ((((k >> 3) ^ (row & 7)) & 15) << 4);
                a[mf] = *reinterpret_cast<const f16x8*>(alds + off);
            }
            #pragma unroll
            for (int mf = 0; mf < 2; ++mf)
                #pragma unroll
                for (int nf = 0; nf < 2; ++nf)
                    acc[mf][nf] = __builtin_amdgcn_mfma_f32_16x16x32_f16(b[nf], a[mf], acc[mf][nf], 0, 0, 0);
        }

        const float* bias = half ? bd : bs;
        #pragma unroll
        for (int mf = 0; mf < 2; ++mf) {
            int row = mf * 16 + lr;
            #pragma unroll
            for (int nf = 0; nf < 2; ++nf) {
                int col = n0w + nf * 16 + nc0;
                float4 bv = *reinterpret_cast<const float4*>(bias + col);
                f16x4 o;
                o[0] = (f16)(acc[mf][nf][0] + bv.x);
                o[1] = (f16)(acc[mf][nf][1] + bv.y);
                o[2] = (f16)(acc[mf][nf][2] + bv.z);
                o[3] = (f16)(acc[mf][nf][3] + bv.w);
                int off = row * 256 + ((col * 2) ^ ((row & 7) << 4));
                *reinterpret_cast<f16x4*>(elds + off) = o;
            }
        }
        __syncthreads();

        f16* outp = half ? hd : hs;
        #pragma unroll
        for (int j = 0; j < 2; ++j) {
            int c = t + j * 256;
            int row = c >> 4;
            int colb = (c & 15) * 16;
            f16x8 vv = *reinterpret_cast<const f16x8*>(elds + row * 256 + (colb ^ ((row & 7) << 4)));
            int grow = row0 + row;
            if (grow < n)
                *reinterpret_cast<f16x8*>(outp + (size_t)grow * 128 + colb / 2) = vv;
        }
        __syncthreads();
    }
}

// fused: blocks [0, buildB) run the one-pass CSR build (4 edges/thread ILP);
// blocks [buildB, ...) run proj1. Branch is block-uniform.
__global__ __launch_bounds__(256) void k_fused(
    const float* __restrict__ x, const f16* __restrict__ Bh,
    const float* __restrict__ bs, const float* __restrict__ bd,
    f16* __restrict__ hs, f16* __restrict__ hd, int n,
    const int* __restrict__ src, const int* __restrict__ dst,
    int* __restrict__ cnt, int* __restrict__ bucket,
    int* __restrict__ ovf, int* __restrict__ ovf_cnt, int e, int buildB)
{
    __shared__ __align__(16) char lds[2 * 32 * 256];
    int b = blockIdx.x;
    if (b < buildB) {
        int base = b * 1024 + threadIdx.x;
        int i0 = base, i1 = base + 256, i2 = base + 512, i3 = base + 768;
        int d0 = (i0 < e) ? dst[i0] : -1;
        int d1 = (i1 < e) ? dst[i1] : -1;
        int d2 = (i2 < e) ? dst[i2] : -1;
        int d3 = (i3 < e) ? dst[i3] : -1;
        int s0 = (i0 < e) ? src[i0] : 0;
        int s1 = (i1 < e) ? src[i1] : 0;
        int s2 = (i2 < e) ? src[i2] : 0;
        int s3 = (i3 < e) ? src[i3] : 0;
        int r0 = (d0 >= 0) ? atomicAdd(&cnt[d0], 1) : 0;
        int r1 = (d1 >= 0) ? atomicAdd(&cnt[d1], 1) : 0;
        int r2 = (d2 >= 0) ? atomicAdd(&cnt[d2], 1) : 0;
        int r3 = (d3 >= 0) ? atomicAdd(&cnt[d3], 1) : 0;
        if (d0 >= 0) { if (r0 < CAP) bucket[(size_t)d0 * CAP + r0] = s0; else { int o = atomicAdd(ovf_cnt, 1); ovf[2*o] = d0; ovf[2*o+1] = s0; } }
        if (d1 >= 0) { if (r1 < CAP) bucket[(size_t)d1 * CAP + r1] = s1; else { int o = atomicAdd(ovf_cnt, 1); ovf[2*o] = d1; ovf[2*o+1] = s1; } }
        if (d2 >= 0) { if (r2 < CAP) bucket[(size_t)d2 * CAP + r2] = s2; else { int o = atomicAdd(ovf_cnt, 1); ovf[2*o] = d2; ovf[2*o+1] = s2; } }
        if (d3 >= 0) { if (r3 < CAP) bucket[(size_t)d3 * CAP + r3] = s3; else { int o = atomicAdd(ovf_cnt, 1); ovf[2*o] = d3; ovf[2*o+1] = s3; } }
    } else {
        proj1_body(lds, b - buildB, x, Bh, bs, bd, hs, hd, n);
    }
}

// layer-1 edge pass: 4 nodes/wave, 16 lanes/node, serial edges + prefetch-2;
// bucket-direct CSR (cap 16 = one cache line/node) with exact overflow scan.
__global__ __launch_bounds__(256) void k_edge1(
    const f16* __restrict__ hs, const f16* __restrict__ hd,
    const f16* __restrict__ attnh,
    const int* __restrict__ cnt, const int* __restrict__ bucket,
    const int* __restrict__ ovf, const int* __restrict__ ovf_cnt,
    f16* __restrict__ out, int n)
{
    int wid = (blockIdx.x * 256 + threadIdx.x) >> 6;
    int lane = threadIdx.x & 63;
    int sub = lane >> 4;
    int q = lane & 15;
    int v = wid * 4 + sub;
    if (v >= n) return;
    int lbase = sub << 4;

    f16x8 hd8 = *reinterpret_cast<const f16x8*>(hd + (size_t)v * 128 + 8 * q);
    f16x8 a8  = *reinterpret_cast<const f16x8*>(attnh + 8 * q);
    const f16x2* a2 = reinterpret_cast<const f16x2*>(&a8);

    int deg = cnt[v];
    int end = deg < CAP ? deg : CAP;
    const int* bk = bucket + (size_t)v * CAP;
    float s = 0.f;
    float acc[8] = {};

    for (int chunk = 0; chunk < end; chunk += 16) {
        int c = end - chunk; if (c > 16) c = 16;
        int idxv = (q < c) ? bk[chunk + q] : 0;

        int u0 = __builtin_amdgcn_ds_bpermute((lbase + 0) << 2, idxv);
        f16x8 hu0 = {};
        if (0 < c) hu0 = *reinterpret_cast<const f16x8*>(hs + (size_t)u0 * 128 + 8 * q);
        int u1 = __builtin_amdgcn_ds_bpermute((lbase + 1) << 2, idxv);
        f16x8 hu1 = {};
        if (1 < c) hu1 = *reinterpret_cast<const f16x8*>(hs + (size_t)u1 * 128 + 8 * q);

        for (int e = 0; e < c; ++e) {
            int u2 = __builtin_amdgcn_ds_bpermute((lbase + ((e + 2) & 15)) << 2, idxv);
            f16x8 hu2 = {};
            if (e + 2 < c) hu2 = *reinterpret_cast<const f16x8*>(hs + (size_t)u2 * 128 + 8 * q);

            f16x8 t  = hu0 + hd8;
            f16x8 at = __builtin_elementwise_abs(t);
            const f16x2* t2  = reinterpret_cast<const f16x2*>(&t);
            const f16x2* at2 = reinterpret_cast<const f16x2*>(&at);
            float p = 0.f, r = 0.f;
            #pragma unroll
            for (int j = 0; j < 4; ++j) {
                p = __builtin_amdgcn_fdot2(t2[j],  a2[j], p, false);
                r = __builtin_amdgcn_fdot2(at2[j], a2[j], r, false);
            }
            float sc = 0.6f * p + 0.4f * r;
            sc += __shfl_xor(sc, 1);
            sc += __shfl_xor(sc, 2);
            float w = __expf(sc);
            s += w;
            #pragma unroll
            for (int j = 0; j < 8; ++j) acc[j] = fmaf(w, (float)hu0[j], acc[j]);
            hu0 = hu1; hu1 = hu2;
        }
    }

    if (deg > CAP) {             // ~0.4% of nodes (Poisson(8) tail)
        int m = *ovf_cnt;
        for (int j = 0; j < m; ++j) {
            if (ovf[2 * j] == v) {
                int u = ovf[2 * j + 1];
                f16x8 hu = *reinterpret_cast<const f16x8*>(hs + (size_t)u * 128 + 8 * q);
                f16x8 t  = hu + hd8;
                f16x8 at = __builtin_elementwise_abs(t);
                const f16x2* t2  = reinterpret_cast<const f16x2*>(&t);
                const f16x2* at2 = reinterpret_cast<const f16x2*>(&at);
                float p = 0.f, r = 0.f;
                #pragma unroll
                for (int jj = 0; jj < 4; ++jj) {
                    p = __builtin_amdgcn_fdot2(t2[jj],  a2[jj], p, false);
                    r = __builtin_amdgcn_fdot2(at2[jj], a2[jj], r, false);
                }
                float sc = 0.6f * p + 0.4f * r;
                sc += __shfl_xor(sc, 1);
                sc += __shfl_xor(sc, 2);
                float w = __expf(sc);
                s += w;
                #pragma unroll
                for (int jj = 0; jj < 8; ++jj) acc[jj] = fmaf(w, (float)hu[jj], acc[jj]);
            }
        }
    }

    float inv = s > 0.f ? 1.f / s : 0.f;
    f16x8 o;
    #pragma unroll
    for (int j = 0; j < 8; ++j) o[j] = (f16)(acc[j] * inv);
    *reinterpret_cast<f16x8*>(out + (size_t)v * 128 + 8 * q) = o;
}

// hs2 = elu(h)@W2s+b2s ; hd2 = elu(h)@W2d+b2d via fp16 MFMA, operand-swapped.
__global__ __launch_bounds__(256) void k_proj2_mfma(
    const f16* __restrict__ h_in, const f16* __restrict__ Bh2,
    const float* __restrict__ bs, const float* __restrict__ bd,
    f16* __restrict__ hs, f16* __restrict__ hd, int n)
{
    __shared__ __align__(16) char lds[128 * 256];
    int t = threadIdx.x;
    int row0 = blockIdx.x * 128;

    {
        int row = t >> 1, half = t & 1;
        bool valid = (row0 + row) < n;
        const f16x8* xr = reinterpret_cast<const f16x8*>(h_in + (size_t)(row0 + row) * 128);
        #pragma unroll
        for (int i = 0; i < 8; ++i) {
            int q = half * 8 + i;
            f16x8 vv = {};
            if (valid) vv = xr[q];
            f16x8 ov;
            #pragma unroll
            for (int j = 0; j < 8; ++j) {
                float f = (float)vv[j];
                f = f > 0.f ? f : __expf(f) - 1.f;
                ov[j] = (f16)f;
            }
            int off = row * 256 + (((q ^ (row & 7)) & 15) << 4);
            *reinterpret_cast<f16x8*>(lds + off) = ov;
        }
    }
    __syncthreads();

    int w = t >> 6, lane = t & 63;
    int lr = lane & 15;
    int kgrp = lane >> 4;

    f32x4 acc[2][2] = {};
    #pragma unroll
    for (int ks = 0; ks < 4; ++ks) {
        int k = ks * 32 + kgrp * 8;
        f16x8 b[2], a[2];
        #pragma unroll
        for (int nf = 0; nf < 2; ++nf)
            b[nf] = *reinterpret_cast<const f16x8*>(Bh2 + (nf * 16 + lr) * 128 + k);
        #pragma unroll
        for (int mf = 0; mf < 2; ++mf) {
            int row = w * 32 + mf * 16 + lr;
            int off = row * 256 + ((((k >> 3) ^ (row & 7)) & 15) << 4);
            a[mf] = *reinterpret_cast<const f16x8*>(lds + off);
        }
        #pragma unroll
        for (int mf = 0; mf < 2; ++mf)
            #pragma unroll
            for (int nf = 0; nf < 2; ++nf)
                acc[mf][nf] = __builtin_amdgcn_mfma_f32_16x16x32_f16(b[nf], a[mf], acc[mf][nf], 0, 0, 0);
    }

    int nc0 = kgrp * 4;
    #pragma unroll
    for (int mf = 0; mf < 2; ++mf) {
        int grow = row0 + w * 32 + mf * 16 + lr;
        if (grow < n) {
            #pragma unroll
            for (int nf = 0; nf < 2; ++nf) {
                const float* bp = (nf == 0) ? (bs + nc0) : (bd + nc0);
                f16* outp = (nf == 0) ? hs : hd;
                float4 bv = *reinterpret_cast<const float4*>(bp);
                f16x4 o;
                o[0] = (f16)(acc[mf][nf][0] + bv.x);
                o[1] = (f16)(acc[mf][nf][1] + bv.y);
                o[2] = (f16)(acc[mf][nf][2] + bv.z);
                o[3] = (f16)(acc[mf][nf][3] + bv.w);
                *reinterpret_cast<f16x4*>(outp + (size_t)grow * 16 + nc0) = o;
            }
        }
    }
}

// layer-2 edge pass: 4 nodes/wave; bucket-direct CSR; overflow handled
// BEFORE the cross-group merge (g==0 group accumulates extras).
__global__ __launch_bounds__(256) void k_edge2(
    const f16* __restrict__ hs, const f16* __restrict__ hd,
    const f16* __restrict__ attnh,
    const int* __restrict__ cnt, const int* __restrict__ bucket,
    const int* __restrict__ ovf, const int* __restrict__ ovf_cnt,
    float* __restrict__ out, int n)
{
    int wid = (blockIdx.x * 256 + threadIdx.x) >> 6;
    int lane = threadIdx.x & 63;
    int sub = lane >> 4;
    int i16 = lane & 15;
    int g = i16 >> 2;
    int slot = i16 & 3;
    int v = wid * 4 + sub;
    if (v >= n) return;
    int lbase = sub << 4;

    f16x4 hd4 = *reinterpret_cast<const f16x4*>(hd + (size_t)v * 16 + 4 * slot);
    f16x4 a4  = *reinterpret_cast<const f16x4*>(attnh + 4 * slot);
    const f16x2* a2 = reinterpret_cast<const f16x2*>(&a4);

    int deg = cnt[v];
    int end = deg < CAP ? deg : CAP;
    const int* bk = bucket + (size_t)v * CAP;
    float s = 0.f;
    float acc[4] = {};

    for (int chunk = 0; chunk < end; chunk += 16) {
        int c = end - chunk; if (c > 16) c = 16;
        int idxv = (i16 < c) ? bk[chunk + i16] : 0;
        int nIter = (c + 3) >> 2;

        int u0 = __builtin_amdgcn_ds_bpermute((lbase + g) << 2, idxv);
        f16x4 hu0 = {};
        if (g < c) hu0 = *reinterpret_cast<const f16x4*>(hs + (size_t)u0 * 16 + 4 * slot);
        int u1 = __builtin_amdgcn_ds_bpermute((lbase + ((g + 4) & 15)) << 2, idxv);
        f16x4 hu1 = {};
        if (g + 4 < c) hu1 = *reinterpret_cast<const f16x4*>(hs + (size_t)u1 * 16 + 4 * slot);

        for (int it = 0; it < nIter; ++it) {
            int e2 = g + 4 * it + 8;
            int u2 = __builtin_amdgcn_ds_bpermute((lbase + (e2 & 15)) << 2, idxv);
            f16x4 hu2 = {};
            if (e2 < c) hu2 = *reinterpret_cast<const f16x4*>(hs + (size_t)u2 * 16 + 4 * slot);

            bool valid = (g + 4 * it) < c;
            f16x4 t  = hu0 + hd4;
            f16x4 at = __builtin_elementwise_abs(t);
            const f16x2* t2  = reinterpret_cast<const f16x2*>(&t);
            const f16x2* at2 = reinterpret_cast<const f16x2*>(&at);
            float p = 0.f, r = 0.f;
            #pragma unroll
            for (int j = 0; j < 2; ++j) {
                p = __builtin_amdgcn_fdot2(t2[j],  a2[j], p, false);
                r = __builtin_amdgcn_fdot2(at2[j], a2[j], r, false);
            }
            float sc = 0.6f * p + 0.4f * r;
            sc += __shfl_xor(sc, 1);
            sc += __shfl_xor(sc, 2);
            float w = valid ? __expf(sc) : 0.f;
            s += w;
            #pragma unroll
            for (int j = 0; j < 4; ++j) acc[j] = fmaf(w, (float)hu0[j], acc[j]);
            hu0 = hu1; hu1 = hu2;
        }
    }

    if (deg > CAP) {             // ~0.4% of nodes; runs BEFORE merge
        int m = *ovf_cnt;
        for (int j = 0; j < m; ++j) {
            int dv = ovf[2 * j];
            if (dv == v) {
                int u = ovf[2 * j + 1];
                f16x4 hu = *reinterpret_cast<const f16x4*>(hs + (size_t)u * 16 + 4 * slot);
                f16x4 t  = hu + hd4;
                f16x4 at = __builtin_elementwise_abs(t);
                const f16x2* t2  = reinterpret_cast<const f16x2*>(&t);
                const f16x2* at2 = reinterpret_cast<const f16x2*>(&at);
                float p = 0.f, r = 0.f;
                #pragma unroll
                for (int jj = 0; jj < 2; ++jj) {
                    p = __builtin_amdgcn_fdot2(t2[jj],  a2[jj], p, false);
                    r = __builtin_amdgcn_fdot2(at2[jj], a2[jj], r, false);
                }
                float sc = 0.6f * p + 0.4f * r;
                sc += __shfl_xor(sc, 1);
                sc += __shfl_xor(sc, 2);
                float w = (g == 0) ? __expf(sc) : 0.f;   // only group 0 accumulates
                s += w;
                #pragma unroll
                for (int jj = 0; jj < 4; ++jj) acc[jj] = fmaf(w, (float)hu[jj], acc[jj]);
            }
        }
    }

    #pragma unroll
    for (int st = 0; st < 2; ++st) {
        int off = 4 << st;
        s += __shfl_xor(s, off);
        #pragma unroll
        for (int j = 0; j < 4; ++j) acc[j] += __shfl_xor(acc[j], off);
    }

    if (g == 0) {
        float inv = s > 0.f ? 1.f / s : 0.f;
        float4 o = make_float4(acc[0] * inv, acc[1] * inv, acc[2] * inv, acc[3] * inv);
        *reinterpret_cast<float4*>(out + (size_t)v * 16 + 4 * slot) = o;
    }
}

extern "C" void kernel_launch(void* const* d_in, const int* in_sizes, int n_in,
                              void* d_out, int out_size, void* d_ws, size_t ws_size,
                              hipStream_t stream) {
    const float* x     = (const float*)d_in[0];
    const int*   ei    = (const int*)d_in[1];
    const float* W1s   = (const float*)d_in[2];
    const float* b1s   = (const float*)d_in[3];
    const float* W1d   = (const float*)d_in[4];
    const float* b1d   = (const float*)d_in[5];
    const float* attn1 = (const float*)d_in[6];
    const float* W2s   = (const float*)d_in[7];
    const float* b2s   = (const float*)d_in[8];
    const float* W2d   = (const float*)d_in[9];
    const float* b2d   = (const float*)d_in[10];
    const float* attn2 = (const float*)d_in[11];

    int n = in_sizes[0] / 128;   // 100000
    int e = in_sizes[1] / 2;     // 800000
    const int* src = ei;
    const int* dst = ei + e;

    char* base = (char*)d_ws;
    size_t off = 0;
    auto alloc = [&](size_t bytes) {
        char* p = base + off;
        off = (off + bytes + 255) & ~255ULL;
        return p;
    };
    int* cnt     = (int*)alloc((size_t)n * 4);
    int* bucket  = (int*)alloc((size_t)n * CAP * 4);
    int* ovf     = (int*)alloc((size_t)e * 8);
    int* ovf_cnt = (int*)alloc(256);
    f16* Bh      = (f16*)alloc(256 * 128 * 2);
    f16* Bh2     = (f16*)alloc(32 * 128 * 2);
    f16* attnh   = (f16*)alloc(144 * 2);
    f16* hs1     = (f16*)alloc((size_t)n * 128 * 2);
    f16* hd1     = (f16*)alloc((size_t)n * 128 * 2);
    f16* out1    = (f16*)alloc((size_t)n * 128 * 2);
    f16* hs2     = (f16*)alloc((size_t)n * 16 * 2);
    f16* hd2     = (f16*)alloc((size_t)n * 16 * 2);
    (void)ws_size;

    int zeroB  = (n + 511) / 512;
    int buildB = (e + 1023) / 1024;          // 782 (4 edges/thread)
    int projB  = (n + 31) / 32;              // 3125

    k_pre<<<289 + zeroB, 128, 0, stream>>>(W1s, W1d, W2s, W2d, attn1, attn2,
                                           Bh, Bh2, attnh, cnt, ovf_cnt, n);
    k_fused<<<buildB + projB, 256, 0, stream>>>(x, Bh, b1s, b1d, hs1, hd1, n,
                                                src, dst, cnt, bucket, ovf, ovf_cnt,
                                                e, buildB);
    k_edge1<<<(n + 15) / 16, 256, 0, stream>>>(hs1, hd1, attnh, cnt, bucket, ovf, ovf_cnt, out1, n);
    k_proj2_mfma<<<(n + 127) / 128, 256, 0, stream>>>(out1, Bh2, b2s, b2d, hs2, hd2, n);
    k_edge2<<<(n + 15) / 16, 256, 0, stream>>>(hs2, hd2, attnh + 128, cnt, bucket, ovf, ovf_cnt, (float*)d_out, n);
}

// Round 23
// 140.005 us; speedup vs baseline: 1.5741x; 1.5741x over previous
//
#include <hip/hip_runtime.h>
#include <hip/hip_bf16.h>

// GATv2 x2: N=100000, E=800000, IN=128, HID=32, H=4, OUT=16
//  r23: CAP=32 (r22's CAP=16 triggered the overflow path on ~370 nodes ->
//  straggler tail, edge1 87us. P(deg>32)=2.5e-11 -> overflow truly never,
//  exact fallback retained). Bucket span = 2 lines/node (halves r21's
//  line-allocation traffic). Fused build+proj1 (r21), edge1/proj2/edge2 = r21.

#define NEG_SLOPE 0.2f
#define CAP 32

typedef _Float16 f16;
typedef _Float16 f16x2 __attribute__((ext_vector_type(2)));
typedef _Float16 f16x4 __attribute__((ext_vector_type(4)));
typedef _Float16 f16x8 __attribute__((ext_vector_type(8)));
typedef float f32x4 __attribute__((ext_vector_type(4)));

// k_pre: b<256 -> Bh fragment-major, b<288 -> Bh2, b==288 -> attnh + zero
// ovf_cnt, b>=289 -> zero cnt.
__global__ __launch_bounds__(128) void k_pre(const float* __restrict__ W1s, const float* __restrict__ W1d,
                                             const float* __restrict__ W2s, const float* __restrict__ W2d,
                                             const float* __restrict__ attn1, const float* __restrict__ attn2,
                                             f16* __restrict__ Bh, f16* __restrict__ Bh2,
                                             f16* __restrict__ attnh, int* __restrict__ cnt,
                                             int* __restrict__ ovf_cnt, int n) {
    int b = blockIdx.x, k = threadIdx.x;
    if (b < 256) {
        float v = (b < 128) ? W1s[k * 128 + b] : W1d[k * 128 + (b - 128)];
        int idx = (((b >> 4) * 16 + (k >> 3)) * 16 + (b & 15)) * 8 + (k & 7);
        Bh[idx] = (f16)v;
    } else if (b < 288) {
        int c = b - 256;
        float v = (c < 16) ? W2s[k * 16 + c] : W2d[k * 16 + (c - 16)];
        Bh2[c * 128 + k] = (f16)v;
    } else if (b == 288) {
        attnh[k] = (f16)attn1[k];
        if (k < 16) attnh[128 + k] = (f16)attn2[k];
        if (k == 0) ovf_cnt[0] = 0;
    } else {
        int i = ((b - 289) * 128 + k) * 4;
        if (i < n) {
            int m = n - i;
            if (m > 4) m = 4;
            for (int j = 0; j < m; ++j) cnt[i + j] = 0;
        }
    }
}

// proj1 body: 32-row tile, both halves sequential, fragment-major B loads,
// LDS-transpose epilogue (r17, verified).
__device__ __forceinline__ void proj1_body(char* lds, int bid,
    const float* __restrict__ x, const f16* __restrict__ Bh,
    const float* __restrict__ bs, const float* __restrict__ bd,
    f16* __restrict__ hs, f16* __restrict__ hd, int n)
{
    char* alds = lds;
    char* elds = lds + 8192;
    int t = threadIdx.x;
    int row0 = bid * 32;

    {
        const float4* x4 = reinterpret_cast<const float4*>(x + (size_t)row0 * 128);
        int rows_here = n - row0; if (rows_here > 32) rows_here = 32;
        int max4 = rows_here * 32;
        #pragma unroll
        for (int i = 0; i < 4; ++i) {
            int idx = t + i * 256;
            float4 v = (idx < max4) ? x4[idx] : make_float4(0.f, 0.f, 0.f, 0.f);
            int row = idx >> 5, k = (idx & 31) * 4;
            int off = row * 256 + ((((k >> 3) ^ (row & 7)) & 15) << 4) + (k & 7) * 2;
            f16x4 h; h[0] = (f16)v.x; h[1] = (f16)v.y; h[2] = (f16)v.z; h[3] = (f16)v.w;
            *reinterpret_cast<f16x4*>(alds + off) = h;
        }
    }
    __syncthreads();

    int w = t >> 6, lane = t & 63;
    int n0w = w * 32;
    int lr = lane & 15;
    int kgrp = lane >> 4;
    int nc0 = kgrp * 4;

    for (int half = 0; half < 2; ++half) {
        f32x4 acc[2][2] = {};
        #pragma unroll
        for (int ks = 0; ks < 4; ++ks) {
            f16x8 b[2], a[2];
            #pragma unroll
            for (int nf = 0; nf < 2; ++nf) {
                int cg = half * 8 + w * 2 + nf;
                const f16* Bf = Bh + (size_t)cg * 2048 + ((ks * 4 + kgrp) * 16 + lr) * 8;
                b[nf] = *reinterpret_cast<const f16x8*>(Bf);
            }
            int k = ks * 32 + kgrp * 8;
            #pragma unroll
            for (int mf = 0; mf < 2; ++mf) {
                int row = mf * 16 + lr;
                int off = row * 256 + ((((k >> 3) ^ (row & 7)) & 15) << 4);
                a[mf] = *reinterpret_cast<const f16x8*>(alds + off);
            }
            #pragma unroll
            for (int mf = 0; mf < 2; ++mf)
                #pragma unroll
                for (int nf = 0; nf < 2; ++nf)
                    acc[mf][nf] = __builtin_amdgcn_mfma_f32_16x16x32_f16(b[nf], a[mf], acc[mf][nf], 0, 0, 0);
        }

        const float* bias = half ? bd : bs;
        #pragma unroll
        for (int mf = 0; mf < 2; ++mf) {
            int row = mf * 16 + lr;
            #pragma unroll
            for (int nf = 0; nf < 2; ++nf) {
                int col = n0w + nf * 16 + nc0;
                float4 bv = *reinterpret_cast<const float4*>(bias + col);
                f16x4 o;
                o[0] = (f16)(acc[mf][nf][0] + bv.x);
                o[1] = (f16)(acc[mf][nf][1] + bv.y);
                o[2] = (f16)(acc[mf][nf][2] + bv.z);
                o[3] = (f16)(acc[mf][nf][3] + bv.w);
                int off = row * 256 + ((col * 2) ^ ((row & 7) << 4));
                *reinterpret_cast<f16x4*>(elds + off) = o;
            }
        }
        __syncthreads();

        f16* outp = half ? hd : hs;
        #pragma unroll
        for (int j = 0; j < 2; ++j) {
            int c = t + j * 256;
            int row = c >> 4;
            int colb = (c & 15) * 16;
            f16x8 vv = *reinterpret_cast<const f16x8*>(elds + row * 256 + (colb ^ ((row & 7) << 4)));
            int grow = row0 + row;
            if (grow < n)
                *reinterpret_cast<f16x8*>(outp + (size_t)grow * 128 + colb / 2) = vv;
        }
        __syncthreads();
    }
}

// fused: blocks [0, buildB) run the one-pass CSR build (4 edges/thread ILP);
// blocks [buildB, ...) run proj1. Branch is block-uniform.
__global__ __launch_bounds__(256) void k_fused(
    const float* __restrict__ x, const f16* __restrict__ Bh,
    const float* __restrict__ bs, const float* __restrict__ bd,
    f16* __restrict__ hs, f16* __restrict__ hd, int n,
    const int* __restrict__ src, const int* __restrict__ dst,
    int* __restrict__ cnt, int* __restrict__ bucket,
    int* __restrict__ ovf, int* __restrict__ ovf_cnt, int e, int buildB)
{
    __shared__ __align__(16) char lds[2 * 32 * 256];
    int b = blockIdx.x;
    if (b < buildB) {
        int base = b * 1024 + threadIdx.x;
        int i0 = base, i1 = base + 256, i2 = base + 512, i3 = base + 768;
        int d0 = (i0 < e) ? dst[i0] : -1;
        int d1 = (i1 < e) ? dst[i1] : -1;
        int d2 = (i2 < e) ? dst[i2] : -1;
        int d3 = (i3 < e) ? dst[i3] : -1;
        int s0 = (i0 < e) ? src[i0] : 0;
        int s1 = (i1 < e) ? src[i1] : 0;
        int s2 = (i2 < e) ? src[i2] : 0;
        int s3 = (i3 < e) ? src[i3] : 0;
        int r0 = (d0 >= 0) ? atomicAdd(&cnt[d0], 1) : 0;
        int r1 = (d1 >= 0) ? atomicAdd(&cnt[d1], 1) : 0;
        int r2 = (d2 >= 0) ? atomicAdd(&cnt[d2], 1) : 0;
        int r3 = (d3 >= 0) ? atomicAdd(&cnt[d3], 1) : 0;
        if (d0 >= 0) { if (r0 < CAP) bucket[(size_t)d0 * CAP + r0] = s0; else { int o = atomicAdd(ovf_cnt, 1); ovf[2*o] = d0; ovf[2*o+1] = s0; } }
        if (d1 >= 0) { if (r1 < CAP) bucket[(size_t)d1 * CAP + r1] = s1; else { int o = atomicAdd(ovf_cnt, 1); ovf[2*o] = d1; ovf[2*o+1] = s1; } }
        if (d2 >= 0) { if (r2 < CAP) bucket[(size_t)d2 * CAP + r2] = s2; else { int o = atomicAdd(ovf_cnt, 1); ovf[2*o] = d2; ovf[2*o+1] = s2; } }
        if (d3 >= 0) { if (r3 < CAP) bucket[(size_t)d3 * CAP + r3] = s3; else { int o = atomicAdd(ovf_cnt, 1); ovf[2*o] = d3; ovf[2*o+1] = s3; } }
    } else {
        proj1_body(lds, b - buildB, x, Bh, bs, bd, hs, hd, n);
    }
}

// layer-1 edge pass: 4 nodes/wave, 16 lanes/node, serial edges + prefetch-2;
// bucket-direct CSR (cap 32, overflow statistically never, exact fallback).
__global__ __launch_bounds__(256) void k_edge1(
    const f16* __restrict__ hs, const f16* __restrict__ hd,
    const f16* __restrict__ attnh,
    const int* __restrict__ cnt, const int* __restrict__ bucket,
    const int* __restrict__ ovf, const int* __restrict__ ovf_cnt,
    f16* __restrict__ out, int n)
{
    int wid = (blockIdx.x * 256 + threadIdx.x) >> 6;
    int lane = threadIdx.x & 63;
    int sub = lane >> 4;
    int q = lane & 15;
    int v = wid * 4 + sub;
    if (v >= n) return;
    int lbase = sub << 4;

    f16x8 hd8 = *reinterpret_cast<const f16x8*>(hd + (size_t)v * 128 + 8 * q);
    f16x8 a8  = *reinterpret_cast<const f16x8*>(attnh + 8 * q);
    const f16x2* a2 = reinterpret_cast<const f16x2*>(&a8);

    int deg = cnt[v];
    int end = deg < CAP ? deg : CAP;
    const int* bk = bucket + (size_t)v * CAP;
    float s = 0.f;
    float acc[8] = {};

    for (int chunk = 0; chunk < end; chunk += 16) {
        int c = end - chunk; if (c > 16) c = 16;
        int idxv = (q < c) ? bk[chunk + q] : 0;

        int u0 = __builtin_amdgcn_ds_bpermute((lbase + 0) << 2, idxv);
        f16x8 hu0 = {};
        if (0 < c) hu0 = *reinterpret_cast<const f16x8*>(hs + (size_t)u0 * 128 + 8 * q);
        int u1 = __builtin_amdgcn_ds_bpermute((lbase + 1) << 2, idxv);
        f16x8 hu1 = {};
        if (1 < c) hu1 = *reinterpret_cast<const f16x8*>(hs + (size_t)u1 * 128 + 8 * q);

        for (int e = 0; e < c; ++e) {
            int u2 = __builtin_amdgcn_ds_bpermute((lbase + ((e + 2) & 15)) << 2, idxv);
            f16x8 hu2 = {};
            if (e + 2 < c) hu2 = *reinterpret_cast<const f16x8*>(hs + (size_t)u2 * 128 + 8 * q);

            f16x8 t  = hu0 + hd8;
            f16x8 at = __builtin_elementwise_abs(t);
            const f16x2* t2  = reinterpret_cast<const f16x2*>(&t);
            const f16x2* at2 = reinterpret_cast<const f16x2*>(&at);
            float p = 0.f, r = 0.f;
            #pragma unroll
            for (int j = 0; j < 4; ++j) {
                p = __builtin_amdgcn_fdot2(t2[j],  a2[j], p, false);
                r = __builtin_amdgcn_fdot2(at2[j], a2[j], r, false);
            }
            float sc = 0.6f * p + 0.4f * r;
            sc += __shfl_xor(sc, 1);
            sc += __shfl_xor(sc, 2);
            float w = __expf(sc);
            s += w;
            #pragma unroll
            for (int j = 0; j < 8; ++j) acc[j] = fmaf(w, (float)hu0[j], acc[j]);
            hu0 = hu1; hu1 = hu2;
        }
    }

    if (deg > CAP) {             // statistically never (P ~ 2.5e-11)
        int m = *ovf_cnt;
        for (int j = 0; j < m; ++j) {
            if (ovf[2 * j] == v) {
                int u = ovf[2 * j + 1];
                f16x8 hu = *reinterpret_cast<const f16x8*>(hs + (size_t)u * 128 + 8 * q);
                f16x8 t  = hu + hd8;
                f16x8 at = __builtin_elementwise_abs(t);
                const f16x2* t2  = reinterpret_cast<const f16x2*>(&t);
                const f16x2* at2 = reinterpret_cast<const f16x2*>(&at);
                float p = 0.f, r = 0.f;
                #pragma unroll
                for (int jj = 0; jj < 4; ++jj) {
                    p = __builtin_amdgcn_fdot2(t2[jj],  a2[jj], p, false);
                    r = __builtin_amdgcn_fdot2(at2[jj], a2[jj], r, false);
                }
                float sc = 0.6f * p + 0.4f * r;
                sc += __shfl_xor(sc, 1);
                sc += __shfl_xor(sc, 2);
                float w = __expf(sc);
                s += w;
                #pragma unroll
                for (int jj = 0; jj < 8; ++jj) acc[jj] = fmaf(w, (float)hu[jj], acc[jj]);
            }
        }
    }

    float inv = s > 0.f ? 1.f / s : 0.f;
    f16x8 o;
    #pragma unroll
    for (int j = 0; j < 8; ++j) o[j] = (f16)(acc[j] * inv);
    *reinterpret_cast<f16x8*>(out + (size_t)v * 128 + 8 * q) = o;
}

// hs2 = elu(h)@W2s+b2s ; hd2 = elu(h)@W2d+b2d via fp16 MFMA, operand-swapped.
__global__ __launch_bounds__(256) void k_proj2_mfma(
    const f16* __restrict__ h_in, const f16* __restrict__ Bh2,
    const float* __restrict__ bs, const float* __restrict__ bd,
    f16* __restrict__ hs, f16* __restrict__ hd, int n)
{
    __shared__ __align__(16) char lds[128 * 256];
    int t = threadIdx.x;
    int row0 = blockIdx.x * 128;

    {
        int row = t >> 1, half = t & 1;
        bool valid = (row0 + row) < n;
        const f16x8* xr = reinterpret_cast<const f16x8*>(h_in + (size_t)(row0 + row) * 128);
        #pragma unroll
        for (int i = 0; i < 8; ++i) {
            int q = half * 8 + i;
            f16x8 vv = {};
            if (valid) vv = xr[q];
            f16x8 ov;
            #pragma unroll
            for (int j = 0; j < 8; ++j) {
                float f = (float)vv[j];
                f = f > 0.f ? f : __expf(f) - 1.f;
                ov[j] = (f16)f;
            }
            int off = row * 256 + (((q ^ (row & 7)) & 15) << 4);
            *reinterpret_cast<f16x8*>(lds + off) = ov;
        }
    }
    __syncthreads();

    int w = t >> 6, lane = t & 63;
    int lr = lane & 15;
    int kgrp = lane >> 4;

    f32x4 acc[2][2] = {};
    #pragma unroll
    for (int ks = 0; ks < 4; ++ks) {
        int k = ks * 32 + kgrp * 8;
        f16x8 b[2], a[2];
        #pragma unroll
        for (int nf = 0; nf < 2; ++nf)
            b[nf] = *reinterpret_cast<const f16x8*>(Bh2 + (nf * 16 + lr) * 128 + k);
        #pragma unroll
        for (int mf = 0; mf < 2; ++mf) {
            int row = w * 32 + mf * 16 + lr;
            int off = row * 256 + ((((k >> 3) ^ (row & 7)) & 15) << 4);
            a[mf] = *reinterpret_cast<const f16x8*>(lds + off);
        }
        #pragma unroll
        for (int mf = 0; mf < 2; ++mf)
            #pragma unroll
            for (int nf = 0; nf < 2; ++nf)
                acc[mf][nf] = __builtin_amdgcn_mfma_f32_16x16x32_f16(b[nf], a[mf], acc[mf][nf], 0, 0, 0);
    }

    int nc0 = kgrp * 4;
    #pragma unroll
    for (int mf = 0; mf < 2; ++mf) {
        int grow = row0 + w * 32 + mf * 16 + lr;
        if (grow < n) {
            #pragma unroll
            for (int nf = 0; nf < 2; ++nf) {
                const float* bp = (nf == 0) ? (bs + nc0) : (bd + nc0);
                f16* outp = (nf == 0) ? hs : hd;
                float4 bv = *reinterpret_cast<const float4*>(bp);
                f16x4 o;
                o[0] = (f16)(acc[mf][nf][0] + bv.x);
                o[1] = (f16)(acc[mf][nf][1] + bv.y);
                o[2] = (f16)(acc[mf][nf][2] + bv.z);
                o[3] = (f16)(acc[mf][nf][3] + bv.w);
                *reinterpret_cast<f16x4*>(outp + (size_t)grow * 16 + nc0) = o;
            }
        }
    }
}

// layer-2 edge pass: 4 nodes/wave; bucket-direct CSR; overflow handled
// BEFORE the cross-group merge (g==0 group accumulates extras).
__global__ __launch_bounds__(256) void k_edge2(
    const f16* __restrict__ hs, const f16* __restrict__ hd,
    const f16* __restrict__ attnh,
    const int* __restrict__ cnt, const int* __restrict__ bucket,
    const int* __restrict__ ovf, const int* __restrict__ ovf_cnt,
    float* __restrict__ out, int n)
{
    int wid = (blockIdx.x * 256 + threadIdx.x) >> 6;
    int lane = threadIdx.x & 63;
    int sub = lane >> 4;
    int i16 = lane & 15;
    int g = i16 >> 2;
    int slot = i16 & 3;
    int v = wid * 4 + sub;
    if (v >= n) return;
    int lbase = sub << 4;

    f16x4 hd4 = *reinterpret_cast<const f16x4*>(hd + (size_t)v * 16 + 4 * slot);
    f16x4 a4  = *reinterpret_cast<const f16x4*>(attnh + 4 * slot);
    const f16x2* a2 = reinterpret_cast<const f16x2*>(&a4);

    int deg = cnt[v];
    int end = deg < CAP ? deg : CAP;
    const int* bk = bucket + (size_t)v * CAP;
    float s = 0.f;
    float acc[4] = {};

    for (int chunk = 0; chunk < end; chunk += 16) {
        int c = end - chunk; if (c > 16) c = 16;
        int idxv = (i16 < c) ? bk[chunk + i16] : 0;
        int nIter = (c + 3) >> 2;

        int u0 = __builtin_amdgcn_ds_bpermute((lbase + g) << 2, idxv);
        f16x4 hu0 = {};
        if (g < c) hu0 = *reinterpret_cast<const f16x4*>(hs + (size_t)u0 * 16 + 4 * slot);
        int u1 = __builtin_amdgcn_ds_bpermute((lbase + ((g + 4) & 15)) << 2, idxv);
        f16x4 hu1 = {};
        if (g + 4 < c) hu1 = *reinterpret_cast<const f16x4*>(hs + (size_t)u1 * 16 + 4 * slot);

        for (int it = 0; it < nIter; ++it) {
            int e2 = g + 4 * it + 8;
            int u2 = __builtin_amdgcn_ds_bpermute((lbase + (e2 & 15)) << 2, idxv);
            f16x4 hu2 = {};
            if (e2 < c) hu2 = *reinterpret_cast<const f16x4*>(hs + (size_t)u2 * 16 + 4 * slot);

            bool valid = (g + 4 * it) < c;
            f16x4 t  = hu0 + hd4;
            f16x4 at = __builtin_elementwise_abs(t);
            const f16x2* t2  = reinterpret_cast<const f16x2*>(&t);
            const f16x2* at2 = reinterpret_cast<const f16x2*>(&at);
            float p = 0.f, r = 0.f;
            #pragma unroll
            for (int j = 0; j < 2; ++j) {
                p = __builtin_amdgcn_fdot2(t2[j],  a2[j], p, false);
                r = __builtin_amdgcn_fdot2(at2[j], a2[j], r, false);
            }
            float sc = 0.6f * p + 0.4f * r;
            sc += __shfl_xor(sc, 1);
            sc += __shfl_xor(sc, 2);
            float w = valid ? __expf(sc) : 0.f;
            s += w;
            #pragma unroll
            for (int j = 0; j < 4; ++j) acc[j] = fmaf(w, (float)hu0[j], acc[j]);
            hu0 = hu1; hu1 = hu2;
        }
    }

    if (deg > CAP) {             // statistically never; runs BEFORE merge
        int m = *ovf_cnt;
        for (int j = 0; j < m; ++j) {
            int dv = ovf[2 * j];
            if (dv == v) {
                int u = ovf[2 * j + 1];
                f16x4 hu = *reinterpret_cast<const f16x4*>(hs + (size_t)u * 16 + 4 * slot);
                f16x4 t  = hu + hd4;
                f16x4 at = __builtin_elementwise_abs(t);
                const f16x2* t2  = reinterpret_cast<const f16x2*>(&t);
                const f16x2* at2 = reinterpret_cast<const f16x2*>(&at);
                float p = 0.f, r = 0.f;
                #pragma unroll
                for (int jj = 0; jj < 2; ++jj) {
                    p = __builtin_amdgcn_fdot2(t2[jj],  a2[jj], p, false);
                    r = __builtin_amdgcn_fdot2(at2[jj], a2[jj], r, false);
                }
                float sc = 0.6f * p + 0.4f * r;
                sc += __shfl_xor(sc, 1);
                sc += __shfl_xor(sc, 2);
                float w = (g == 0) ? __expf(sc) : 0.f;   // only group 0 accumulates
                s += w;
                #pragma unroll
                for (int jj = 0; jj < 4; ++jj) acc[jj] = fmaf(w, (float)hu[jj], acc[jj]);
            }
        }
    }

    #pragma unroll
    for (int st = 0; st < 2; ++st) {
        int off = 4 << st;
        s += __shfl_xor(s, off);
        #pragma unroll
        for (int j = 0; j < 4; ++j) acc[j] += __shfl_xor(acc[j], off);
    }

    if (g == 0) {
        float inv = s > 0.f ? 1.f / s : 0.f;
        float4 o = make_float4(acc[0] * inv, acc[1] * inv, acc[2] * inv, acc[3] * inv);
        *reinterpret_cast<float4*>(out + (size_t)v * 16 + 4 * slot) = o;
    }
}

extern "C" void kernel_launch(void* const* d_in, const int* in_sizes, int n_in,
                              void* d_out, int out_size, void* d_ws, size_t ws_size,
                              hipStream_t stream) {
    const float* x     = (const float*)d_in[0];
    const int*   ei    = (const int*)d_in[1];
    const float* W1s   = (const float*)d_in[2];
    const float* b1s   = (const float*)d_in[3];
    const float* W1d   = (const float*)d_in[4];
    const float* b1d   = (const float*)d_in[5];
    const float* attn1 = (const float*)d_in[6];
    const float* W2s   = (const float*)d_in[7];
    const float* b2s   = (const float*)d_in[8];
    const float* W2d   = (const float*)d_in[9];
    const float* b2d   = (const float*)d_in[10];
    const float* attn2 = (const float*)d_in[11];

    int n = in_sizes[0] / 128;   // 100000
    int e = in_sizes[1] / 2;     // 800000
    const int* src = ei;
    const int* dst = ei + e;

    char* base = (char*)d_ws;
    size_t off = 0;
    auto alloc = [&](size_t bytes) {
        char* p = base + off;
        off = (off + bytes + 255) & ~255ULL;
        return p;
    };
    int* cnt     = (int*)alloc((size_t)n * 4);
    int* bucket  = (int*)alloc((size_t)n * CAP * 4);
    int* ovf     = (int*)alloc((size_t)e * 8);
    int* ovf_cnt = (int*)alloc(256);
    f16* Bh      = (f16*)alloc(256 * 128 * 2);
    f16* Bh2     = (f16*)alloc(32 * 128 * 2);
    f16* attnh   = (f16*)alloc(144 * 2);
    f16* hs1     = (f16*)alloc((size_t)n * 128 * 2);
    f16* hd1     = (f16*)alloc((size_t)n * 128 * 2);
    f16* out1    = (f16*)alloc((size_t)n * 128 * 2);
    f16* hs2     = (f16*)alloc((size_t)n * 16 * 2);
    f16* hd2     = (f16*)alloc((size_t)n * 16 * 2);
    (void)ws_size;

    int zeroB  = (n + 511) / 512;
    int buildB = (e + 1023) / 1024;          // 782 (4 edges/thread)
    int projB  = (n + 31) / 32;              // 3125

    k_pre<<<289 + zeroB, 128, 0, stream>>>(W1s, W1d, W2s, W2d, attn1, attn2,
                                           Bh, Bh2, attnh, cnt, ovf_cnt, n);
    k_fused<<<buildB + projB, 256, 0, stream>>>(x, Bh, b1s, b1d, hs1, hd1, n,
                                                src, dst, cnt, bucket, ovf, ovf_cnt,
                                                e, buildB);
    k_edge1<<<(n + 15) / 16, 256, 0, stream>>>(hs1, hd1, attnh, cnt, bucket, ovf, ovf_cnt, out1, n);
    k_proj2_mfma<<<(n + 127) / 128, 256, 0, stream>>>(out1, Bh2, b2s, b2d, hs2, hd2, n);
    k_edge2<<<(n + 15) / 16, 256, 0, stream>>>(hs2, hd2, attnh + 128, cnt, bucket, ovf, ovf_cnt, (float*)d_out, n);
}